// Round 4
// baseline (262.901 us; speedup 1.0000x reference)
//
#include <hip/hip_runtime.h>

// Problem structure (see reference):
//  - conv weight is uniform ones/25 across ALL (out,in) channel pairs =>
//    every blurred output channel equals s = (1/25) * 5x5-boxsum(sum_c img[c]).
//  - r=g=b=s => X=Y=Z=s in the Lab conversion => fX==fY==fZ => a==b==128
//    for BOTH images => a/b channels cancel in the MSE. Only L survives.
//  - result = sum_{b,y,x} ((L1-L2)/100)^2 / (B*3*H*W)
//    with L(s) = s > 0.008856 ? 116*cbrt(s)-16 : 903.3*s,
//    s = clip(w0 * boxsum, 0, 1), w0 = weight[0] (= 1/25).

constexpr int TILE  = 64;
constexpr int HALO  = 2;
constexpr int EXT   = TILE + 2 * HALO;   // 68
constexpr int IMG_H = 512;
constexpr int IMG_W = 512;
constexpr int BATCH = 32;
constexpr float THR = 0.008856f;

__global__ __launch_bounds__(256)
void lcol_mse_kernel(const float* __restrict__ img1,
                     const float* __restrict__ img2,
                     const float* __restrict__ weight,
                     float* __restrict__ out)
{
    __shared__ float cs[EXT * EXT];        // 18496 B, channel-sum staging (reused per image)
    __shared__ float hb[2][EXT * TILE];    // 2 * 17408 B, horizontal 5-tap sums per image
    __shared__ float wpart[4];

    const int tid = threadIdx.x;
    const int bx0 = blockIdx.x * TILE;
    const int by0 = blockIdx.y * TILE;
    const int b   = blockIdx.z;

    const float w0 = weight[0];            // uniform tap value (1/25)

    const size_t plane = (size_t)IMG_H * IMG_W;
    const float* bases[2] = { img1 + (size_t)b * 3 * plane,
                              img2 + (size_t)b * 3 * plane };

    for (int img = 0; img < 2; ++img) {
        const float* base = bases[img];
        // phase 1: load channel-sum with zero padding into cs
        for (int i = tid; i < EXT * EXT; i += 256) {
            int row = i / EXT;
            int col = i - row * EXT;
            int gy = by0 + row - HALO;
            int gx = bx0 + col - HALO;
            float v = 0.f;
            if ((unsigned)gy < (unsigned)IMG_H && (unsigned)gx < (unsigned)IMG_W) {
                size_t o = (size_t)gy * IMG_W + gx;
                v = base[o] + base[plane + o] + base[2 * plane + o];
            }
            cs[i] = v;
        }
        __syncthreads();
        // phase 2: horizontal 5-tap sums (68 rows x 64 cols)
        float* h = hb[img];
        for (int i = tid; i < EXT * TILE; i += 256) {
            int y = i >> 6;           // 0..67
            int x = i & 63;           // 0..63
            const float* r = &cs[y * EXT + x];
            h[i] = r[0] + r[1] + r[2] + r[3] + r[4];
        }
        __syncthreads();              // h ready; cs free for next image
    }

    // phase 3: vertical 5-tap, L curve, squared diff, accumulate
    float acc = 0.f;
    #pragma unroll
    for (int k = 0; k < 16; ++k) {
        int i = tid + k * 256;        // 0..4095
        int y = i >> 6;               // 0..63  (wave = one row -> conflict-free)
        int x = i & 63;
        const float* p1 = &hb[0][y * TILE + x];
        const float* p2 = &hb[1][y * TILE + x];
        float v1 = (p1[0] + p1[TILE] + p1[2*TILE] + p1[3*TILE] + p1[4*TILE]) * w0;
        float v2 = (p2[0] + p2[TILE] + p2[2*TILE] + p2[3*TILE] + p2[4*TILE]) * w0;
        v1 = fminf(fmaxf(v1, 0.f), 1.f);
        v2 = fminf(fmaxf(v2, 0.f), 1.f);
        float L1 = (v1 > THR) ? (116.f * cbrtf(v1) - 16.f) : (903.3f * v1);
        float L2 = (v2 > THR) ? (116.f * cbrtf(v2) - 16.f) : (903.3f * v2);
        float d = L1 - L2;
        acc += d * d;
    }

    // wave (64-lane) shuffle reduction, then cross-wave via LDS
    #pragma unroll
    for (int off = 32; off; off >>= 1) acc += __shfl_down(acc, off);
    if ((tid & 63) == 0) wpart[tid >> 6] = acc;
    __syncthreads();
    if (tid == 0) {
        float s = wpart[0] + wpart[1] + wpart[2] + wpart[3];
        // mean over B*3*H*W elements; L channel scaled by 1/100; a/b = 0.
        const float scale = (float)(1.0 / (10000.0 * (double)BATCH * 3.0 * IMG_H * IMG_W));
        atomicAdd(out, s * scale);
    }
}

extern "C" void kernel_launch(void* const* d_in, const int* in_sizes, int n_in,
                              void* d_out, int out_size, void* d_ws, size_t ws_size,
                              hipStream_t stream) {
    const float* img1   = (const float*)d_in[0];
    const float* img2   = (const float*)d_in[1];
    const float* weight = (const float*)d_in[2];
    float* out = (float*)d_out;

    // d_out is poisoned to 0xAA before every timed replay -> zero it ourselves.
    hipMemsetAsync(out, 0, sizeof(float), stream);

    dim3 grid(IMG_W / TILE, IMG_H / TILE, BATCH);
    lcol_mse_kernel<<<grid, dim3(256), 0, stream>>>(img1, img2, weight, out);
}

// Round 5
// 235.043 us; speedup vs baseline: 1.1185x; 1.1185x over previous
//
#include <hip/hip_runtime.h>

// Collapsed problem (verified on HW, round 4, absmax 0.0):
//  uniform ones/25 conv weight => all blurred channels equal
//  s = w0 * boxsum5x5(sum_c img[c]); r=g=b => X=Y=Z => a==b==128 both images
//  => only L survives: result = sum ((L1-L2)/100)^2 / (B*3*H*W),
//  L(s) = s>0.008856 ? 116*cbrt(s)-16 : 903.3*s, s = clip(w0*boxsum, 0, 1).
//
// Round-5 redesign: LDS 53.8KB -> 19.6KB (8 blocks/CU, whole grid resident),
// float4 staging loads, separable 5x5 via 5-wide LDS reads + rolling register
// window (no staged intermediate).

constexpr int TILE  = 64;
constexpr int HALO  = 2;
constexpr int ROWS  = TILE + 2 * HALO;   // 68 staged rows
constexpr int CPAD  = 72;                // staged cols: aligned float4 span [bx0-4, bx0+68)
constexpr int NF4   = CPAD / 4;          // 18 float4 per row
constexpr int IMG_H = 512;
constexpr int IMG_W = 512;
constexpr int BATCH = 32;
constexpr float THR = 0.008856f;

__global__ __launch_bounds__(256, 8)   // force VGPR<=64: 8 waves/SIMD budget
void lcol_mse_kernel(const float* __restrict__ img1,
                     const float* __restrict__ img2,
                     const float* __restrict__ weight,
                     float* __restrict__ out)
{
    __shared__ float cs[ROWS * CPAD];    // 19584 B -> 8 blocks/CU
    __shared__ float wpart[4];

    const int tid = threadIdx.x;
    const int bx0 = blockIdx.x * TILE;
    const int by0 = blockIdx.y * TILE;
    const int b   = blockIdx.z;
    const float wtap = weight[0];        // uniform tap (1/25)

    const size_t plane = (size_t)IMG_H * IMG_W;
    const float* bases[2] = { img1 + (size_t)b * 3 * plane,
                              img2 + (size_t)b * 3 * plane };

    const int x  = tid & 63;             // owned column (wave = one row-group, stride-1)
    const int r0 = (tid >> 6) * 16;      // first owned output row (16 per thread)

    float L1[16];                        // img1 L values, statically indexed
    float acc = 0.f;

    for (int img = 0; img < 2; ++img) {
        const float* base = bases[img];

        // phase A: stage channel-sum, 68 rows x 18 aligned float4 (zero-padded).
        // gx0 = bx0-4+4k is always a multiple of 4 => each float4 fully in or out.
        for (int n = tid; n < ROWS * NF4; n += 256) {
            int row = n / NF4;
            int k   = n - row * NF4;
            int gy  = by0 + row - HALO;
            int gx  = bx0 + 4 * k - 4;
            float4 v = make_float4(0.f, 0.f, 0.f, 0.f);
            if ((unsigned)gy < (unsigned)IMG_H && (unsigned)gx < (unsigned)IMG_W) {
                const float* p = base + (size_t)gy * IMG_W + gx;
                float4 r  = *(const float4*)(p);
                float4 g  = *(const float4*)(p + plane);
                float4 bl = *(const float4*)(p + 2 * plane);
                v = make_float4(r.x + g.x + bl.x, r.y + g.y + bl.y,
                                r.z + g.z + bl.z, r.w + g.w + bl.w);
            }
            *(float4*)&cs[row * CPAD + 4 * k] = v;
        }
        __syncthreads();

        // phase B: per-column rolling 5x5. H(i) = 5-wide horizontal sum at staged
        // row i; lanes read consecutive addresses -> conflict-free.
        const float* colbase = &cs[x + 2];
        float h0 = colbase[(r0    ) * CPAD] + colbase[(r0    ) * CPAD + 1] + colbase[(r0    ) * CPAD + 2] + colbase[(r0    ) * CPAD + 3] + colbase[(r0    ) * CPAD + 4];
        float h1 = colbase[(r0 + 1) * CPAD] + colbase[(r0 + 1) * CPAD + 1] + colbase[(r0 + 1) * CPAD + 2] + colbase[(r0 + 1) * CPAD + 3] + colbase[(r0 + 1) * CPAD + 4];
        float h2 = colbase[(r0 + 2) * CPAD] + colbase[(r0 + 2) * CPAD + 1] + colbase[(r0 + 2) * CPAD + 2] + colbase[(r0 + 2) * CPAD + 3] + colbase[(r0 + 2) * CPAD + 4];
        float h3 = colbase[(r0 + 3) * CPAD] + colbase[(r0 + 3) * CPAD + 1] + colbase[(r0 + 3) * CPAD + 2] + colbase[(r0 + 3) * CPAD + 3] + colbase[(r0 + 3) * CPAD + 4];
        #pragma unroll
        for (int k = 0; k < 16; ++k) {
            const float* p = colbase + (r0 + 4 + k) * CPAD;
            float h4 = p[0] + p[1] + p[2] + p[3] + p[4];
            float v  = (h0 + h1 + h2 + h3 + h4) * wtap;
            v = fminf(fmaxf(v, 0.f), 1.f);
            float L = (v > THR) ? (116.f * cbrtf(v) - 16.f) : (903.3f * v);
            if (img == 0) L1[k] = L;
            else { float d = L1[k] - L; acc += d * d; }
            h0 = h1; h1 = h2; h2 = h3; h3 = h4;
        }
        __syncthreads();   // cs free for next image / L1 complete
    }

    // wave shuffle reduction, then cross-wave via LDS, one atomic per block
    #pragma unroll
    for (int off = 32; off; off >>= 1) acc += __shfl_down(acc, off);
    if ((tid & 63) == 0) wpart[tid >> 6] = acc;
    __syncthreads();
    if (tid == 0) {
        float s = wpart[0] + wpart[1] + wpart[2] + wpart[3];
        const float scale = (float)(1.0 / (10000.0 * (double)BATCH * 3.0 * IMG_H * IMG_W));
        atomicAdd(out, s * scale);
    }
}

extern "C" void kernel_launch(void* const* d_in, const int* in_sizes, int n_in,
                              void* d_out, int out_size, void* d_ws, size_t ws_size,
                              hipStream_t stream) {
    const float* img1   = (const float*)d_in[0];
    const float* img2   = (const float*)d_in[1];
    const float* weight = (const float*)d_in[2];
    float* out = (float*)d_out;

    // d_out is poisoned to 0xAA before every timed replay -> zero it ourselves.
    hipMemsetAsync(out, 0, sizeof(float), stream);

    dim3 grid(IMG_W / TILE, IMG_H / TILE, BATCH);   // 8 x 8 x 32 = 2048 blocks
    lcol_mse_kernel<<<grid, dim3(256), 0, stream>>>(img1, img2, weight, out);
}

// Round 6
// 228.506 us; speedup vs baseline: 1.1505x; 1.0286x over previous
//
#include <hip/hip_runtime.h>

// Collapsed problem (HW-verified, rounds 4-5, absmax 0.0):
//  uniform ones/25 conv weight => all blurred channels equal
//  s = w0 * boxsum5x5(sum_c img[c]); r=g=b => a==b==128 both images =>
//  only L survives: result = sum ((L1-L2)/100)^2 / (B*3*H*W).
//
// Round-6: software-pipelined persistent blocks. 1024 blocks (all resident,
// 4/CU), 2 tiles/block = 4 stage-units. Double-buffered LDS; per step:
// {issue next unit's 15 float4 loads to regs} -> {compute current unit from
// LDS} -> {vmcnt drain, ds_write next} -> barrier. VMEM overlaps VALU/LDS.

constexpr int TILE  = 64;
constexpr int HALO  = 2;
constexpr int ROWS  = TILE + 2 * HALO;   // 68
constexpr int CPAD  = 72;                // aligned float4 span [bx0-4, bx0+68)
constexpr int NF4   = CPAD / 4;          // 18
constexpr int NITER = ROWS * NF4;        // 1224
constexpr int IMG_H = 512;
constexpr int IMG_W = 512;
constexpr int BATCH = 32;
constexpr int NBLOCKS = 1024;            // 4 blocks/CU * 256 CU, all resident
constexpr float THR = 0.008856f;

__device__ __forceinline__ void issue_loads(const float* __restrict__ base,
                                            int by0, int bx0, int tid,
                                            float4 rv[5], float4 gv[5], float4 bv[5])
{
    const size_t plane = (size_t)IMG_H * IMG_W;
    #pragma unroll
    for (int k = 0; k < 5; ++k) {
        int n    = tid + 256 * k;
        int row  = n / NF4;
        int col4 = (n - row * NF4) * 4;
        int gy   = by0 + row - HALO;
        int gx   = bx0 + col4 - 4;       // multiple of 4 => float4 fully in or out
        float4 z = make_float4(0.f, 0.f, 0.f, 0.f);
        rv[k] = z; gv[k] = z; bv[k] = z;
        if (n < NITER && (unsigned)gy < (unsigned)IMG_H && (unsigned)gx < (unsigned)IMG_W) {
            const float* p = base + (size_t)gy * IMG_W + gx;
            rv[k] = *(const float4*)(p);
            gv[k] = *(const float4*)(p + plane);
            bv[k] = *(const float4*)(p + 2 * plane);
        }
    }
}

__device__ __forceinline__ void write_stage(float* __restrict__ buf, int tid,
                                            const float4 rv[5], const float4 gv[5],
                                            const float4 bv[5])
{
    #pragma unroll
    for (int k = 0; k < 5; ++k) {
        int n = tid + 256 * k;
        if (n < NITER) {
            int row  = n / NF4;
            int col4 = (n - row * NF4) * 4;
            float4 v;
            v.x = rv[k].x + gv[k].x + bv[k].x;
            v.y = rv[k].y + gv[k].y + bv[k].y;
            v.z = rv[k].z + gv[k].z + bv[k].z;
            v.w = rv[k].w + gv[k].w + bv[k].w;
            *(float4*)&buf[row * CPAD + col4] = v;
        }
    }
}

__device__ __forceinline__ void compute_unit(const float* __restrict__ buf,
                                             int x, int r0, float wtap, bool first,
                                             float L1[16], float& acc)
{
    const float* colbase = buf + x + 2;
    float h0 = colbase[(r0    ) * CPAD] + colbase[(r0    ) * CPAD + 1] + colbase[(r0    ) * CPAD + 2] + colbase[(r0    ) * CPAD + 3] + colbase[(r0    ) * CPAD + 4];
    float h1 = colbase[(r0 + 1) * CPAD] + colbase[(r0 + 1) * CPAD + 1] + colbase[(r0 + 1) * CPAD + 2] + colbase[(r0 + 1) * CPAD + 3] + colbase[(r0 + 1) * CPAD + 4];
    float h2 = colbase[(r0 + 2) * CPAD] + colbase[(r0 + 2) * CPAD + 1] + colbase[(r0 + 2) * CPAD + 2] + colbase[(r0 + 2) * CPAD + 3] + colbase[(r0 + 2) * CPAD + 4];
    float h3 = colbase[(r0 + 3) * CPAD] + colbase[(r0 + 3) * CPAD + 1] + colbase[(r0 + 3) * CPAD + 2] + colbase[(r0 + 3) * CPAD + 3] + colbase[(r0 + 3) * CPAD + 4];
    #pragma unroll
    for (int k = 0; k < 16; ++k) {
        const float* p = colbase + (r0 + 4 + k) * CPAD;
        float h4 = p[0] + p[1] + p[2] + p[3] + p[4];
        float v  = (h0 + h1 + h2 + h3 + h4) * wtap;
        v = fminf(fmaxf(v, 0.f), 1.f);
        float L = (v > THR) ? (116.f * cbrtf(v) - 16.f) : (903.3f * v);
        if (first) L1[k] = L;
        else { float d = L1[k] - L; acc += d * d; }
        h0 = h1; h1 = h2; h2 = h3; h3 = h4;
    }
}

__global__ __launch_bounds__(256, 4)   // cap VGPR at 128: 4 blocks/CU (LDS-capped too)
void lcol_mse_kernel(const float* __restrict__ img1,
                     const float* __restrict__ img2,
                     const float* __restrict__ weight,
                     float* __restrict__ out)
{
    __shared__ float cs[2][ROWS * CPAD];   // 2 x 19584 B double buffer
    __shared__ float wpart[4];

    const int tid = threadIdx.x;
    const int x   = tid & 63;              // owned column
    const int r0  = (tid >> 6) * 16;       // first owned output row
    const float wtap = weight[0];
    const size_t plane = (size_t)IMG_H * IMG_W;

    // 4 stage-units: (tile0,img1),(tile0,img2),(tile1,img1),(tile1,img2)
    int by0s[2], bx0s[2];
    const float* bases[4];
    #pragma unroll
    for (int t = 0; t < 2; ++t) {
        int tile = (int)blockIdx.x + t * NBLOCKS;   // 0..2047, each exactly once
        int b    = tile >> 6;                        // batch 0..31
        int rem  = tile & 63;
        by0s[t]  = (rem >> 3) * TILE;
        bx0s[t]  = (rem & 7) * TILE;
        bases[2 * t]     = img1 + (size_t)b * 3 * plane;
        bases[2 * t + 1] = img2 + (size_t)b * 3 * plane;
    }

    float L1[16];
    float acc = 0.f;
    float4 rv[5], gv[5], bv[5];

    // prologue: stage unit 0 into buffer 0
    issue_loads(bases[0], by0s[0], bx0s[0], tid, rv, gv, bv);
    write_stage(cs[0], tid, rv, gv, bv);
    __syncthreads();

    // pipelined steady state: issue(u+1) early, compute(u), write(u+1) late
    #pragma unroll
    for (int u = 0; u < 4; ++u) {
        if (u < 3)
            issue_loads(bases[u + 1], by0s[(u + 1) >> 1], bx0s[(u + 1) >> 1],
                        tid, rv, gv, bv);
        compute_unit(cs[u & 1], x, r0, wtap, (u & 1) == 0, L1, acc);
        if (u < 3)
            write_stage(cs[(u + 1) & 1], tid, rv, gv, bv);
        __syncthreads();
    }

    // wave shuffle reduction -> cross-wave LDS -> one atomic per block
    #pragma unroll
    for (int off = 32; off; off >>= 1) acc += __shfl_down(acc, off);
    if ((tid & 63) == 0) wpart[tid >> 6] = acc;
    __syncthreads();
    if (tid == 0) {
        float s = wpart[0] + wpart[1] + wpart[2] + wpart[3];
        const float scale = (float)(1.0 / (10000.0 * (double)BATCH * 3.0 * IMG_H * IMG_W));
        atomicAdd(out, s * scale);
    }
}

extern "C" void kernel_launch(void* const* d_in, const int* in_sizes, int n_in,
                              void* d_out, int out_size, void* d_ws, size_t ws_size,
                              hipStream_t stream) {
    const float* img1   = (const float*)d_in[0];
    const float* img2   = (const float*)d_in[1];
    const float* weight = (const float*)d_in[2];
    float* out = (float*)d_out;

    // d_out is poisoned to 0xAA before every timed replay -> zero it ourselves.
    hipMemsetAsync(out, 0, sizeof(float), stream);

    lcol_mse_kernel<<<dim3(NBLOCKS), dim3(256), 0, stream>>>(img1, img2, weight, out);
}

// Round 7
// 222.136 us; speedup vs baseline: 1.1835x; 1.0287x over previous
//
#include <hip/hip_runtime.h>

// Collapsed problem (HW-verified, rounds 4-6, absmax 0.0):
//  uniform ones/25 conv weight => all blurred channels equal
//  s = w0 * boxsum5x5(sum_c img[c]); r=g=b => a==b==128 both images =>
//  only L survives: result = sum ((L1-L2)/100)^2 / (B*3*H*W).
//
// Round-7: kill the same-address atomic (1024-2048 serialized device-scope
// atomicAdds to one word — suspected data-location-independent tail, per
// round-6 L3-resident replay running at identical 86us). Blocks write
// partials to d_ws; a 1-block reduce kernel finishes. Also back to 2048
// blocks x 1 tile (2 pipelined units) for shorter critical paths and
// scheduler slack.

constexpr int TILE  = 64;
constexpr int HALO  = 2;
constexpr int ROWS  = TILE + 2 * HALO;   // 68
constexpr int CPAD  = 72;                // aligned float4 span [bx0-4, bx0+68)
constexpr int NF4   = CPAD / 4;          // 18
constexpr int NITER = ROWS * NF4;        // 1224
constexpr int IMG_H = 512;
constexpr int IMG_W = 512;
constexpr int BATCH = 32;
constexpr int NTILES = 2048;             // 8 x 8 x 32
constexpr float THR = 0.008856f;

__device__ __forceinline__ void issue_loads(const float* __restrict__ base,
                                            int by0, int bx0, int tid,
                                            float4 rv[5], float4 gv[5], float4 bv[5])
{
    const size_t plane = (size_t)IMG_H * IMG_W;
    #pragma unroll
    for (int k = 0; k < 5; ++k) {
        int n    = tid + 256 * k;
        int row  = n / NF4;
        int col4 = (n - row * NF4) * 4;
        int gy   = by0 + row - HALO;
        int gx   = bx0 + col4 - 4;       // multiple of 4 => float4 fully in or out
        float4 z = make_float4(0.f, 0.f, 0.f, 0.f);
        rv[k] = z; gv[k] = z; bv[k] = z;
        if (n < NITER && (unsigned)gy < (unsigned)IMG_H && (unsigned)gx < (unsigned)IMG_W) {
            const float* p = base + (size_t)gy * IMG_W + gx;
            rv[k] = *(const float4*)(p);
            gv[k] = *(const float4*)(p + plane);
            bv[k] = *(const float4*)(p + 2 * plane);
        }
    }
}

__device__ __forceinline__ void write_stage(float* __restrict__ buf, int tid,
                                            const float4 rv[5], const float4 gv[5],
                                            const float4 bv[5])
{
    #pragma unroll
    for (int k = 0; k < 5; ++k) {
        int n = tid + 256 * k;
        if (n < NITER) {
            int row  = n / NF4;
            int col4 = (n - row * NF4) * 4;
            float4 v;
            v.x = rv[k].x + gv[k].x + bv[k].x;
            v.y = rv[k].y + gv[k].y + bv[k].y;
            v.z = rv[k].z + gv[k].z + bv[k].z;
            v.w = rv[k].w + gv[k].w + bv[k].w;
            *(float4*)&buf[row * CPAD + col4] = v;
        }
    }
}

__device__ __forceinline__ void compute_unit(const float* __restrict__ buf,
                                             int x, int r0, float wtap, bool first,
                                             float L1[16], float& acc)
{
    const float* colbase = buf + x + 2;
    float h0 = colbase[(r0    ) * CPAD] + colbase[(r0    ) * CPAD + 1] + colbase[(r0    ) * CPAD + 2] + colbase[(r0    ) * CPAD + 3] + colbase[(r0    ) * CPAD + 4];
    float h1 = colbase[(r0 + 1) * CPAD] + colbase[(r0 + 1) * CPAD + 1] + colbase[(r0 + 1) * CPAD + 2] + colbase[(r0 + 1) * CPAD + 3] + colbase[(r0 + 1) * CPAD + 4];
    float h2 = colbase[(r0 + 2) * CPAD] + colbase[(r0 + 2) * CPAD + 1] + colbase[(r0 + 2) * CPAD + 2] + colbase[(r0 + 2) * CPAD + 3] + colbase[(r0 + 2) * CPAD + 4];
    float h3 = colbase[(r0 + 3) * CPAD] + colbase[(r0 + 3) * CPAD + 1] + colbase[(r0 + 3) * CPAD + 2] + colbase[(r0 + 3) * CPAD + 3] + colbase[(r0 + 3) * CPAD + 4];
    #pragma unroll
    for (int k = 0; k < 16; ++k) {
        const float* p = colbase + (r0 + 4 + k) * CPAD;
        float h4 = p[0] + p[1] + p[2] + p[3] + p[4];
        float v  = (h0 + h1 + h2 + h3 + h4) * wtap;
        v = fminf(fmaxf(v, 0.f), 1.f);
        float L = (v > THR) ? (116.f * cbrtf(v) - 16.f) : (903.3f * v);
        if (first) L1[k] = L;
        else { float d = L1[k] - L; acc += d * d; }
        h0 = h1; h1 = h2; h2 = h3; h3 = h4;
    }
}

__global__ __launch_bounds__(256, 4)
void lcol_mse_kernel(const float* __restrict__ img1,
                     const float* __restrict__ img2,
                     const float* __restrict__ weight,
                     float* __restrict__ part)
{
    __shared__ float cs[2][ROWS * CPAD];   // 2 x 19584 B double buffer
    __shared__ float wpart[4];

    const int tid = threadIdx.x;
    const int x   = tid & 63;
    const int r0  = (tid >> 6) * 16;
    const float wtap = weight[0];
    const size_t plane = (size_t)IMG_H * IMG_W;

    const int tile = (int)blockIdx.x;      // 0..2047
    const int b    = tile >> 6;
    const int rem  = tile & 63;
    const int by0  = (rem >> 3) * TILE;
    const int bx0  = (rem & 7) * TILE;
    const float* base1 = img1 + (size_t)b * 3 * plane;
    const float* base2 = img2 + (size_t)b * 3 * plane;

    float L1[16];
    float acc = 0.f;
    float4 rv[5], gv[5], bv[5];

    // prologue: stage img1 into buffer 0
    issue_loads(base1, by0, bx0, tid, rv, gv, bv);
    write_stage(cs[0], tid, rv, gv, bv);
    __syncthreads();

    // pipelined: issue img2 early, compute img1, write img2 late
    issue_loads(base2, by0, bx0, tid, rv, gv, bv);
    compute_unit(cs[0], x, r0, wtap, true, L1, acc);
    write_stage(cs[1], tid, rv, gv, bv);
    __syncthreads();

    compute_unit(cs[1], x, r0, wtap, false, L1, acc);

    // block reduction -> one partial per tile (no atomics anywhere)
    #pragma unroll
    for (int off = 32; off; off >>= 1) acc += __shfl_down(acc, off);
    if ((tid & 63) == 0) wpart[tid >> 6] = acc;
    __syncthreads();
    if (tid == 0)
        part[tile] = wpart[0] + wpart[1] + wpart[2] + wpart[3];
}

__global__ __launch_bounds__(256)
void lcol_reduce_kernel(const float* __restrict__ part, float* __restrict__ out)
{
    __shared__ float w[4];
    const int tid = threadIdx.x;
    float s = 0.f;
    #pragma unroll
    for (int k = 0; k < NTILES / 256; ++k) s += part[tid + 256 * k];
    #pragma unroll
    for (int off = 32; off; off >>= 1) s += __shfl_down(s, off);
    if ((tid & 63) == 0) w[tid >> 6] = s;
    __syncthreads();
    if (tid == 0) {
        const float scale = (float)(1.0 / (10000.0 * (double)BATCH * 3.0 * IMG_H * IMG_W));
        out[0] = (w[0] + w[1] + w[2] + w[3]) * scale;
    }
}

extern "C" void kernel_launch(void* const* d_in, const int* in_sizes, int n_in,
                              void* d_out, int out_size, void* d_ws, size_t ws_size,
                              hipStream_t stream) {
    const float* img1   = (const float*)d_in[0];
    const float* img2   = (const float*)d_in[1];
    const float* weight = (const float*)d_in[2];
    float* out  = (float*)d_out;
    float* part = (float*)d_ws;            // 2048 floats of scratch

    lcol_mse_kernel<<<dim3(NTILES), dim3(256), 0, stream>>>(img1, img2, weight, part);
    lcol_reduce_kernel<<<dim3(1), dim3(256), 0, stream>>>(part, out);
}